// Round 8
// baseline (290.275 us; speedup 1.0000x reference)
//
#include <hip/hip_runtime.h>
#include <hip/hip_bf16.h>

#define B_ 2
#define S_ 2048
#define E_ 1024
#define H_ 16
#define D_ 64
#define M_ (B_*S_)   // 4096

typedef __attribute__((ext_vector_type(8))) short bf16x8;   // 8 bf16 in 4 VGPRs
typedef __attribute__((ext_vector_type(4))) float f32x4;
typedef __attribute__((ext_vector_type(8))) unsigned short u16x8;
typedef __attribute__((ext_vector_type(4))) unsigned short u16x4;

// native cast -> compiler emits v_cvt_pk_bf16_f32 pairs (m240)
__device__ __forceinline__ unsigned short f2bf_hw(float f) {
  union { __hip_bfloat16 h; unsigned short u; } c;
  c.h = __float2bfloat16(f);
  return c.u;
}

__device__ __forceinline__ void gload_lds16(const void* g, void* l) {
  __builtin_amdgcn_global_load_lds(
      (const __attribute__((address_space(1))) void*)g,
      (__attribute__((address_space(3))) void*)l, 16, 0, 0);
}

// ---------------- fused fp32 -> bf16 convert (h + 4 weights) -------------
__global__ __launch_bounds__(256) void cvt_all(const float* __restrict__ h,
                                               const float* __restrict__ Wq,
                                               const float* __restrict__ Wk,
                                               const float* __restrict__ Wv,
                                               const float* __restrict__ Wo,
                                               unsigned short* __restrict__ dst,
                                               float qscale) {
  int i = blockIdx.x * 256 + threadIdx.x;   // 0 .. 2^21-1 (float4 units)
  const float4* src4;
  int idx;
  float scale = 1.f;
  if (i < (1 << 20)) {                       // h: 2^20 float4
    src4 = (const float4*)h; idx = i;
  } else {
    int t = i - (1 << 20);
    int j = t >> 18;                          // which W (2^18 float4 each)
    idx = t & ((1 << 18) - 1);
    src4 = (const float4*)((j == 0) ? Wq : (j == 1) ? Wk : (j == 2) ? Wv : Wo);
    if (j == 0) scale = qscale;
  }
  float4 v = src4[idx];
  u16x4 o;
  o[0] = f2bf_hw(v.x * scale);
  o[1] = f2bf_hw(v.y * scale);
  o[2] = f2bf_hw(v.z * scale);
  o[3] = f2bf_hw(v.w * scale);
  ((u16x4*)dst)[i] = o;
}

// ---------------- GEMM core: C[m,n] = sum_k A[m,k] * W[n,k] -------------
// 128x128 tile, BK=32, 256 threads = 4 waves (2x2), each wave 64x64.
// LDS rows 64B: XOR-swizzle chunk c -> c ^ ((row>>1)&3), pre-swizzled at the
// global source (gload_lds dest stays linear), same swizzle at read.
template<int OUT_BF16>
__device__ __forceinline__ void gemm_body(const unsigned short* __restrict__ A,
                                          const unsigned short* __restrict__ W,
                                          void* __restrict__ Cv,
                                          int row0, int col0, int N, int K,
                                          unsigned short* As, unsigned short* Bs) {
  const int tid = threadIdx.x;
  const int lane = tid & 63, wave = tid >> 6;
  const int wr = wave >> 1, wc = wave & 1;
  const int lq = lane & 15, lg = lane >> 4;
  f32x4 acc[4][4] = {};

  for (int kt = 0; kt < K; kt += 32) {
#pragma unroll
    for (int i = 0; i < 2; ++i) {
      int t = tid + i * 256;
      int rr = t >> 2;
      int sch = (t & 3) ^ ((rr >> 1) & 3);   // pre-swizzled source chunk
      gload_lds16(A + (size_t)(row0 + rr) * K + kt + sch * 8, &As[t * 8]);
      gload_lds16(W + (size_t)(col0 + rr) * K + kt + sch * 8, &Bs[t * 8]);
    }
    __syncthreads();
    bf16x8 af[4], bfr[4];
#pragma unroll
    for (int mi = 0; mi < 4; ++mi) {
      int row = wr * 64 + mi * 16 + lq;
      af[mi] = *(const bf16x8*)&As[row * 32 + (lg ^ ((row >> 1) & 3)) * 8];
    }
#pragma unroll
    for (int ni = 0; ni < 4; ++ni) {
      int row = wc * 64 + ni * 16 + lq;
      bfr[ni] = *(const bf16x8*)&Bs[row * 32 + (lg ^ ((row >> 1) & 3)) * 8];
    }
#pragma unroll
    for (int mi = 0; mi < 4; ++mi)
#pragma unroll
      for (int ni = 0; ni < 4; ++ni)
        acc[mi][ni] = __builtin_amdgcn_mfma_f32_16x16x32_bf16(af[mi], bfr[ni], acc[mi][ni], 0, 0, 0);
    __syncthreads();
  }

#pragma unroll
  for (int mi = 0; mi < 4; ++mi)
#pragma unroll
    for (int ni = 0; ni < 4; ++ni) {
      int row = row0 + wr * 64 + mi * 16 + lg * 4;
      int col = col0 + wc * 64 + ni * 16 + lq;
#pragma unroll
      for (int r = 0; r < 4; ++r) {
        float v = acc[mi][ni][r];
        if (OUT_BF16) ((unsigned short*)Cv)[(size_t)(row + r) * N + col] = f2bf_hw(v);
        else          ((float*)Cv)[(size_t)(row + r) * N + col] = v;
      }
    }
}

// Fused QKV projection: grid (M/128, 3*E/128). blockIdx.y selects matrix.
__global__ __launch_bounds__(256) void gemm_qkv(const unsigned short* __restrict__ A,
                                                const unsigned short* __restrict__ Wq,
                                                const unsigned short* __restrict__ Wk,
                                                const unsigned short* __restrict__ Wv,
                                                unsigned short* __restrict__ Qb,
                                                unsigned short* __restrict__ Kb,
                                                unsigned short* __restrict__ Vb) {
  __shared__ unsigned short As[128 * 32];
  __shared__ unsigned short Bs[128 * 32];
  const int mat = blockIdx.y >> 3;
  const int col0 = (blockIdx.y & 7) * 128;
  const unsigned short* W = (mat == 0) ? Wq : (mat == 1) ? Wk : Wv;
  unsigned short* C = (mat == 0) ? Qb : (mat == 1) ? Kb : Vb;
  gemm_body<1>(A, W, C, blockIdx.x * 128, col0, E_, E_, As, Bs);
}

__global__ __launch_bounds__(256) void gemm_out(const unsigned short* __restrict__ A,
                                                const unsigned short* __restrict__ W,
                                                float* __restrict__ C) {
  __shared__ unsigned short As[128 * 32];
  __shared__ unsigned short Bs[128 * 32];
  gemm_body<0>(A, W, C, blockIdx.x * 128, blockIdx.y * 128, E_, E_, As, Bs);
}

// ---------------- V [B,S,E](bf16) -> VT [B*H*D, S](bf16) -----------------
__global__ __launch_bounds__(256) void transpose_v(const unsigned short* __restrict__ V,
                                                   unsigned short* __restrict__ VT) {
  __shared__ unsigned short tile[64][72];
  const int tid = threadIdx.x;
  const int s0 = blockIdx.x * 64;
  const int h = blockIdx.y;
  const int b = blockIdx.z;
  const int r = tid >> 3;
  const int c = (tid & 7) * 8;
  const unsigned short* src = V + ((size_t)(b * S_) + s0) * E_ + h * 64;
#pragma unroll
  for (int i = 0; i < 2; ++i) {
    int rr = r + i * 32;
    u16x8 v = *(const u16x8*)(src + (size_t)rr * E_ + c);
#pragma unroll
    for (int j = 0; j < 8; ++j) tile[rr][c + j] = v[j];
  }
  __syncthreads();
  unsigned short* dst = VT + ((size_t)((b * H_ + h) * 64)) * S_ + s0;
#pragma unroll
  for (int i = 0; i < 2; ++i) {
    int d = r + i * 32;
    u16x8 o;
#pragma unroll
    for (int j = 0; j < 8; ++j) o[j] = tile[c + j][d];
    *(u16x8*)(dst + (size_t)d * S_ + c) = o;
  }
}

// ---------------- flash attention ---------------------------------------
// grid: (S/64, B*H). 256 threads = 4 waves; wave w owns q rows [w*16, w*16+16).
// Score scale 0.125*log2(e) folded into W_q -> softmax in exp2 domain.
// Swapped QK^T: S^T = mfma(K, Q). Ks/Vs XOR-swizzled (logical chunk c at
// slot c^(row&7)); T14 reg-staged async split: SINGLE LDS buffer (occupancy!),
// global loads for tile t+1 issued before tile t's compute, ds_write after
// barrier. Defer-max (T13, THR=8 log2). setprio(1) around MFMA (T5).
__global__ __launch_bounds__(256) void attn(const unsigned short* __restrict__ Q,
                                            const unsigned short* __restrict__ K,
                                            const unsigned short* __restrict__ VT,
                                            unsigned short* __restrict__ ctx) {
  __shared__ unsigned short Ks[64 * 64];       // [key][d], swizzled
  __shared__ unsigned short Vs[64 * 64];       // [dv][key], swizzled
  __shared__ unsigned short Ps[4][16 * 72];    // per wave: [q][key], padded
  const int tid = threadIdx.x, lane = tid & 63, wave = tid >> 6;
  const int lq = lane & 15, lg = lane >> 4;
  const int bh = blockIdx.y, b = bh >> 4, h = bh & 15;
  const int q0 = blockIdx.x * 64;

  const unsigned short* Qbase = Q + ((size_t)(b * S_) + q0 + wave * 16 + lq) * E_ + h * 64;
  bf16x8 qf0 = *(const bf16x8*)(Qbase + lg * 8);
  bf16x8 qf1 = *(const bf16x8*)(Qbase + 32 + lg * 8);
  const unsigned short* Kbase = K + (size_t)(b * S_) * E_ + h * 64;
  const unsigned short* Vtb = VT + (size_t)((b * H_ + h) * 64) * S_;
  unsigned short* Pw = Ps[wave];

  // per-thread staging slice: 2 K-chunks + 2 V-chunks of 16B
  const int r0_ = tid >> 3, ch_ = tid & 7;          // i=0 slice
  const int r1_ = (tid + 256) >> 3;                 // i=1 slice (same ch)
  uint4 kreg[2], vreg[2];

  auto LOADREG = [&](int kc) {
    kreg[0] = *(const uint4*)(Kbase + (size_t)(kc + r0_) * E_ + ch_ * 8);
    vreg[0] = *(const uint4*)(Vtb + (size_t)r0_ * S_ + kc + ch_ * 8);
    kreg[1] = *(const uint4*)(Kbase + (size_t)(kc + r1_) * E_ + ch_ * 8);
    vreg[1] = *(const uint4*)(Vtb + (size_t)r1_ * S_ + kc + ch_ * 8);
  };
  auto WRITELDS = [&]() {
    *(uint4*)&Ks[(r0_ * 8 + (ch_ ^ (r0_ & 7))) * 8] = kreg[0];
    *(uint4*)&Vs[(r0_ * 8 + (ch_ ^ (r0_ & 7))) * 8] = vreg[0];
    *(uint4*)&Ks[(r1_ * 8 + (ch_ ^ (r1_ & 7))) * 8] = kreg[1];
    *(uint4*)&Vs[(r1_ * 8 + (ch_ ^ (r1_ & 7))) * 8] = vreg[1];
  };

  f32x4 oacc[4] = {};
  float m_run = -1e30f, l_run = 0.f;

  LOADREG(0);
  WRITELDS();
  __syncthreads();

  for (int kc = 0; kc < S_; kc += 64) {
    const bool pref = (kc + 64 < S_);
    if (pref) LOADREG(kc + 64);   // issue early; lands during compute below

    // S^T[key][q] for 64 keys (log2-domain scores)
    f32x4 st[4] = {};
    __builtin_amdgcn_s_setprio(1);
#pragma unroll
    for (int mf = 0; mf < 4; ++mf) {
      int row = mf * 16 + lq;
      bf16x8 kf0 = *(const bf16x8*)&Ks[row * 64 + ((lg ^ (row & 7)) * 8)];
      bf16x8 kf1 = *(const bf16x8*)&Ks[row * 64 + (((4 + lg) ^ (row & 7)) * 8)];
      st[mf] = __builtin_amdgcn_mfma_f32_16x16x32_bf16(kf0, qf0, st[mf], 0, 0, 0);
      st[mf] = __builtin_amdgcn_mfma_f32_16x16x32_bf16(kf1, qf1, st[mf], 0, 0, 0);
    }
    __builtin_amdgcn_s_setprio(0);

    // tile max over 64 keys for q = lq (tree; lanes lg=0..3 hold disjoint keys)
    float c0 = fmaxf(fmaxf(st[0][0], st[0][1]), fmaxf(st[0][2], st[0][3]));
    float c1 = fmaxf(fmaxf(st[1][0], st[1][1]), fmaxf(st[1][2], st[1][3]));
    float c2 = fmaxf(fmaxf(st[2][0], st[2][1]), fmaxf(st[2][2], st[2][3]));
    float c3 = fmaxf(fmaxf(st[3][0], st[3][1]), fmaxf(st[3][2], st[3][3]));
    float cm = fmaxf(fmaxf(c0, c1), fmaxf(c2, c3));
    cm = fmaxf(cm, __shfl_xor(cm, 16));
    cm = fmaxf(cm, __shfl_xor(cm, 32));

    // defer-max (T13): rescale only when max grew by > 8 (log2 units).
    if (!__all(cm - m_run <= 8.f)) {
      float m_new = fmaxf(m_run, cm);
      float alpha = __builtin_amdgcn_exp2f(m_run - m_new);
#pragma unroll
      for (int r = 0; r < 4; ++r) {
        float ar = __shfl(alpha, lg * 4 + r);
#pragma unroll
        for (int nf = 0; nf < 4; ++nf) oacc[nf][r] *= ar;
      }
      l_run *= alpha;
      m_run = m_new;
    }

    float ls = 0.f;
#pragma unroll
    for (int mf = 0; mf < 4; ++mf) {
      u16x4 pb;
#pragma unroll
      for (int r = 0; r < 4; ++r) {
        float p = __builtin_amdgcn_exp2f(st[mf][r] - m_run);
        ls += p;
        pb[r] = f2bf_hw(p);
      }
      *(u16x4*)&Pw[lq * 72 + mf * 16 + lg * 4] = pb;  // P[q][key]
    }
    ls += __shfl_xor(ls, 16);
    ls += __shfl_xor(ls, 32);
    l_run += ls;
    asm volatile("s_waitcnt lgkmcnt(0)" ::: "memory");

    // O[q][dv] += P @ V
    __builtin_amdgcn_s_setprio(1);
#pragma unroll
    for (int ks = 0; ks < 2; ++ks) {
      bf16x8 pf = *(const bf16x8*)&Pw[lq * 72 + ks * 32 + lg * 8];
#pragma unroll
      for (int nf = 0; nf < 4; ++nf) {
        int row = nf * 16 + lq;
        bf16x8 vf = *(const bf16x8*)&Vs[row * 64 + (((ks * 4 + lg) ^ (row & 7)) * 8)];
        oacc[nf] = __builtin_amdgcn_mfma_f32_16x16x32_bf16(pf, vf, oacc[nf], 0, 0, 0);
      }
    }
    __builtin_amdgcn_s_setprio(0);

    if (pref) {
      __syncthreads();     // all waves done reading Ks/Vs for this tile
      WRITELDS();          // compiler waits on kreg/vreg (already landed)
      __syncthreads();     // writes visible to all waves
    }
  }

  // normalize + store ctx (bf16, [B,S,E] layout)
#pragma unroll
  for (int r = 0; r < 4; ++r) {
    float lr = __shfl(l_run, lg * 4 + r);
    float inv = 1.f / lr;
#pragma unroll
    for (int nf = 0; nf < 4; ++nf) {
      ctx[((size_t)(b * S_) + q0 + wave * 16 + lg * 4 + r) * E_ + h * 64 + nf * 16 + lq] =
          f2bf_hw(oacc[nf][r] * inv);
    }
  }
}

// ---------------- launch -------------------------------------------------
extern "C" void kernel_launch(void* const* d_in, const int* in_sizes, int n_in,
                              void* d_out, int out_size, void* d_ws, size_t ws_size,
                              hipStream_t stream) {
  const float* h  = (const float*)d_in[0];
  const float* Wq = (const float*)d_in[1];
  const float* Wk = (const float*)d_in[2];
  const float* Wv = (const float*)d_in[3];
  const float* Wo = (const float*)d_in[4];
  float* out = (float*)d_out;
  char* ws = (char*)d_ws;

  const size_t SZ_H = (size_t)M_ * E_ * 2;   // 8 MiB
  const size_t SZ_W = (size_t)E_ * E_ * 2;   // 2 MiB
  unsigned short* hb  = (unsigned short*)(ws);
  unsigned short* wqb = (unsigned short*)(ws + SZ_H);
  unsigned short* wkb = (unsigned short*)(ws + SZ_H + SZ_W);
  unsigned short* wvb = (unsigned short*)(ws + SZ_H + 2 * SZ_W);
  unsigned short* wob = (unsigned short*)(ws + SZ_H + 3 * SZ_W);
  unsigned short* Qb  = (unsigned short*)(ws + SZ_H + 4 * SZ_W);
  unsigned short* Kb  = (unsigned short*)(ws + 2 * SZ_H + 4 * SZ_W);
  unsigned short* Vb  = (unsigned short*)(ws + 3 * SZ_H + 4 * SZ_W);
  unsigned short* VTb = hb;   // h no longer needed after QKV GEMMs
  unsigned short* Cb  = Vb;   // V no longer needed after transpose

  // one fused convert for h + all weights; fold 0.125*log2(e) into W_q
  const float QSCALE = 0.125f * 1.44269504f;
  cvt_all<<<8192, 256, 0, stream>>>(h, Wq, Wk, Wv, Wo, hb, QSCALE);

  // fused QKV projection: 3 blocks/CU instead of 1
  gemm_qkv<<<dim3(M_ / 128, 3 * E_ / 128), 256, 0, stream>>>(hb, wqb, wkb, wvb, Qb, Kb, Vb);

  transpose_v<<<dim3(S_ / 64, H_, B_), 256, 0, stream>>>(Vb, VTb);

  attn<<<dim3(S_ / 64, B_ * H_), 256, 0, stream>>>(Qb, Kb, VTb, Cb);

  gemm_out<<<dim3(M_ / 128, E_ / 128), 256, 0, stream>>>(Cb, wob, out);
}

// Round 9
// 209.147 us; speedup vs baseline: 1.3879x; 1.3879x over previous
//
#include <hip/hip_runtime.h>
#include <hip/hip_bf16.h>

#define B_ 2
#define S_ 2048
#define E_ 1024
#define H_ 16
#define D_ 64
#define M_ (B_*S_)   // 4096

typedef __attribute__((ext_vector_type(8))) short bf16x8;   // 8 bf16 in 4 VGPRs
typedef __attribute__((ext_vector_type(4))) float f32x4;
typedef __attribute__((ext_vector_type(8))) unsigned short u16x8;
typedef __attribute__((ext_vector_type(4))) unsigned short u16x4;

// native cast -> compiler emits v_cvt_pk_bf16_f32 pairs (m240)
__device__ __forceinline__ unsigned short f2bf_hw(float f) {
  union { __hip_bfloat16 h; unsigned short u; } c;
  c.h = __float2bfloat16(f);
  return c.u;
}

__device__ __forceinline__ void gload_lds16(const void* g, void* l) {
  __builtin_amdgcn_global_load_lds(
      (const __attribute__((address_space(1))) void*)g,
      (__attribute__((address_space(3))) void*)l, 16, 0, 0);
}

// ---------------- fused fp32 -> bf16 convert (h + 4 weights) -------------
__global__ __launch_bounds__(256) void cvt_all(const float* __restrict__ h,
                                               const float* __restrict__ Wq,
                                               const float* __restrict__ Wk,
                                               const float* __restrict__ Wv,
                                               const float* __restrict__ Wo,
                                               unsigned short* __restrict__ dst,
                                               float qscale) {
  int i = blockIdx.x * 256 + threadIdx.x;   // 0 .. 2^21-1 (float4 units)
  const float4* src4;
  int idx;
  float scale = 1.f;
  if (i < (1 << 20)) {                       // h: 2^20 float4
    src4 = (const float4*)h; idx = i;
  } else {
    int t = i - (1 << 20);
    int j = t >> 18;                          // which W (2^18 float4 each)
    idx = t & ((1 << 18) - 1);
    src4 = (const float4*)((j == 0) ? Wq : (j == 1) ? Wk : (j == 2) ? Wv : Wo);
    if (j == 0) scale = qscale;
  }
  float4 v = src4[idx];
  u16x4 o;
  o[0] = f2bf_hw(v.x * scale);
  o[1] = f2bf_hw(v.y * scale);
  o[2] = f2bf_hw(v.z * scale);
  o[3] = f2bf_hw(v.w * scale);
  ((u16x4*)dst)[i] = o;
}

// ---------------- GEMM core: C[m,n] = sum_k A[m,k] * W[n,k] -------------
// 128x128 tile, BK=32, 256 threads = 4 waves (2x2), each wave 64x64.
// LDS rows 64B: XOR-swizzle chunk c -> c ^ ((row>>1)&3), pre-swizzled at the
// global source (gload_lds dest stays linear), same swizzle at read.
template<int OUT_BF16>
__device__ __forceinline__ void gemm_body(const unsigned short* __restrict__ A,
                                          const unsigned short* __restrict__ W,
                                          void* __restrict__ Cv,
                                          int row0, int col0, int N, int K,
                                          unsigned short* As, unsigned short* Bs) {
  const int tid = threadIdx.x;
  const int lane = tid & 63, wave = tid >> 6;
  const int wr = wave >> 1, wc = wave & 1;
  const int lq = lane & 15, lg = lane >> 4;
  f32x4 acc[4][4] = {};

  for (int kt = 0; kt < K; kt += 32) {
#pragma unroll
    for (int i = 0; i < 2; ++i) {
      int t = tid + i * 256;
      int rr = t >> 2;
      int sch = (t & 3) ^ ((rr >> 1) & 3);   // pre-swizzled source chunk
      gload_lds16(A + (size_t)(row0 + rr) * K + kt + sch * 8, &As[t * 8]);
      gload_lds16(W + (size_t)(col0 + rr) * K + kt + sch * 8, &Bs[t * 8]);
    }
    __syncthreads();
    bf16x8 af[4], bfr[4];
#pragma unroll
    for (int mi = 0; mi < 4; ++mi) {
      int row = wr * 64 + mi * 16 + lq;
      af[mi] = *(const bf16x8*)&As[row * 32 + (lg ^ ((row >> 1) & 3)) * 8];
    }
#pragma unroll
    for (int ni = 0; ni < 4; ++ni) {
      int row = wc * 64 + ni * 16 + lq;
      bfr[ni] = *(const bf16x8*)&Bs[row * 32 + (lg ^ ((row >> 1) & 3)) * 8];
    }
    __builtin_amdgcn_s_setprio(1);
#pragma unroll
    for (int mi = 0; mi < 4; ++mi)
#pragma unroll
      for (int ni = 0; ni < 4; ++ni)
        acc[mi][ni] = __builtin_amdgcn_mfma_f32_16x16x32_bf16(af[mi], bfr[ni], acc[mi][ni], 0, 0, 0);
    __builtin_amdgcn_s_setprio(0);
    __syncthreads();
  }

#pragma unroll
  for (int mi = 0; mi < 4; ++mi)
#pragma unroll
    for (int ni = 0; ni < 4; ++ni) {
      int row = row0 + wr * 64 + mi * 16 + lg * 4;
      int col = col0 + wc * 64 + ni * 16 + lq;
#pragma unroll
      for (int r = 0; r < 4; ++r) {
        float v = acc[mi][ni][r];
        if (OUT_BF16) ((unsigned short*)Cv)[(size_t)(row + r) * N + col] = f2bf_hw(v);
        else          ((float*)Cv)[(size_t)(row + r) * N + col] = v;
      }
    }
}

// Fused QKV projection: grid (M/128, 3*E/128). blockIdx.y selects matrix.
__global__ __launch_bounds__(256) void gemm_qkv(const unsigned short* __restrict__ A,
                                                const unsigned short* __restrict__ Wq,
                                                const unsigned short* __restrict__ Wk,
                                                const unsigned short* __restrict__ Wv,
                                                unsigned short* __restrict__ Qb,
                                                unsigned short* __restrict__ Kb,
                                                unsigned short* __restrict__ Vb) {
  __shared__ unsigned short As[128 * 32];
  __shared__ unsigned short Bs[128 * 32];
  const int mat = blockIdx.y >> 3;
  const int col0 = (blockIdx.y & 7) * 128;
  const unsigned short* W = (mat == 0) ? Wq : (mat == 1) ? Wk : Wv;
  unsigned short* C = (mat == 0) ? Qb : (mat == 1) ? Kb : Vb;
  gemm_body<1>(A, W, C, blockIdx.x * 128, col0, E_, E_, As, Bs);
}

__global__ __launch_bounds__(256) void gemm_out(const unsigned short* __restrict__ A,
                                                const unsigned short* __restrict__ W,
                                                float* __restrict__ C) {
  __shared__ unsigned short As[128 * 32];
  __shared__ unsigned short Bs[128 * 32];
  gemm_body<0>(A, W, C, blockIdx.x * 128, blockIdx.y * 128, E_, E_, As, Bs);
}

// ---------------- V [B,S,E](bf16) -> VT [B*H*D, S](bf16) -----------------
__global__ __launch_bounds__(256) void transpose_v(const unsigned short* __restrict__ V,
                                                   unsigned short* __restrict__ VT) {
  __shared__ unsigned short tile[64][72];
  const int tid = threadIdx.x;
  const int s0 = blockIdx.x * 64;
  const int h = blockIdx.y;
  const int b = blockIdx.z;
  const int r = tid >> 3;
  const int c = (tid & 7) * 8;
  const unsigned short* src = V + ((size_t)(b * S_) + s0) * E_ + h * 64;
#pragma unroll
  for (int i = 0; i < 2; ++i) {
    int rr = r + i * 32;
    u16x8 v = *(const u16x8*)(src + (size_t)rr * E_ + c);
#pragma unroll
    for (int j = 0; j < 8; ++j) tile[rr][c + j] = v[j];
  }
  __syncthreads();
  unsigned short* dst = VT + ((size_t)((b * H_ + h) * 64)) * S_ + s0;
#pragma unroll
  for (int i = 0; i < 2; ++i) {
    int d = r + i * 32;
    u16x8 o;
#pragma unroll
    for (int j = 0; j < 8; ++j) o[j] = tile[c + j][d];
    *(u16x8*)(dst + (size_t)d * S_ + c) = o;
  }
}

// ---------------- flash attention ---------------------------------------
// grid: (S/64, B*H). 256 threads = 4 waves; wave w owns q rows [w*16, w*16+16).
// Score scale 0.125*log2(e) folded into W_q -> softmax in exp2 domain.
// Swapped QK^T: S^T = mfma(K, Q). Ks/Vs XOR-swizzled (chunk ^ row&7),
// pre-swizzled at global source, gload_lds single-buffer (round-6 proven:
// reg-staging spills [R8], dbuf kills occupancy [R7]).
// Defer-max (T13, THR=8 log2), native bf16 casts, setprio around MFMA (T5).
__global__ __launch_bounds__(256) void attn(const unsigned short* __restrict__ Q,
                                            const unsigned short* __restrict__ K,
                                            const unsigned short* __restrict__ VT,
                                            unsigned short* __restrict__ ctx) {
  __shared__ unsigned short Ks[64 * 64];       // [key][d], swizzled
  __shared__ unsigned short Vs[64 * 64];       // [dv][key], swizzled
  __shared__ unsigned short Ps[4][16 * 72];    // per wave: [q][key], padded
  const int tid = threadIdx.x, lane = tid & 63, wave = tid >> 6;
  const int lq = lane & 15, lg = lane >> 4;
  const int bh = blockIdx.y, b = bh >> 4, h = bh & 15;
  const int q0 = blockIdx.x * 64;

  const unsigned short* Qbase = Q + ((size_t)(b * S_) + q0 + wave * 16 + lq) * E_ + h * 64;
  bf16x8 qf0 = *(const bf16x8*)(Qbase + lg * 8);
  bf16x8 qf1 = *(const bf16x8*)(Qbase + 32 + lg * 8);
  const unsigned short* Kbase = K + (size_t)(b * S_) * E_ + h * 64;
  const unsigned short* Vtb = VT + (size_t)((b * H_ + h) * 64) * S_;
  unsigned short* Pw = Ps[wave];

  f32x4 oacc[4] = {};
  float m_run = -1e30f, l_run = 0.f;

  for (int kc = 0; kc < S_; kc += 64) {
    __syncthreads();
#pragma unroll
    for (int i = 0; i < 2; ++i) {
      int tt = tid + i * 256;
      int r = tt >> 3;
      int sch = (tt & 7) ^ (r & 7);          // pre-swizzled source chunk
      gload_lds16(Kbase + (size_t)(kc + r) * E_ + sch * 8, &Ks[tt * 8]);
      gload_lds16(Vtb + (size_t)r * S_ + kc + sch * 8, &Vs[tt * 8]);
    }
    __syncthreads();

    // S^T[key][q] for 64 keys (log2-domain scores)
    f32x4 st[4] = {};
    __builtin_amdgcn_s_setprio(1);
#pragma unroll
    for (int mf = 0; mf < 4; ++mf) {
      int row = mf * 16 + lq;
      bf16x8 kf0 = *(const bf16x8*)&Ks[row * 64 + ((lg ^ (row & 7)) * 8)];
      bf16x8 kf1 = *(const bf16x8*)&Ks[row * 64 + (((4 + lg) ^ (row & 7)) * 8)];
      st[mf] = __builtin_amdgcn_mfma_f32_16x16x32_bf16(kf0, qf0, st[mf], 0, 0, 0);
      st[mf] = __builtin_amdgcn_mfma_f32_16x16x32_bf16(kf1, qf1, st[mf], 0, 0, 0);
    }
    __builtin_amdgcn_s_setprio(0);

    // tile max over 64 keys for q = lq (tree; lanes lg=0..3 hold disjoint keys)
    float c0 = fmaxf(fmaxf(st[0][0], st[0][1]), fmaxf(st[0][2], st[0][3]));
    float c1 = fmaxf(fmaxf(st[1][0], st[1][1]), fmaxf(st[1][2], st[1][3]));
    float c2 = fmaxf(fmaxf(st[2][0], st[2][1]), fmaxf(st[2][2], st[2][3]));
    float c3 = fmaxf(fmaxf(st[3][0], st[3][1]), fmaxf(st[3][2], st[3][3]));
    float cm = fmaxf(fmaxf(c0, c1), fmaxf(c2, c3));
    cm = fmaxf(cm, __shfl_xor(cm, 16));
    cm = fmaxf(cm, __shfl_xor(cm, 32));

    // defer-max (T13): rescale only when max grew by > 8 (log2 units).
    // P bounded by 2^8; f32 l_run/oacc have ample headroom.
    if (!__all(cm - m_run <= 8.f)) {
      float m_new = fmaxf(m_run, cm);
      float alpha = __builtin_amdgcn_exp2f(m_run - m_new);
#pragma unroll
      for (int r = 0; r < 4; ++r) {
        float ar = __shfl(alpha, lg * 4 + r);
#pragma unroll
        for (int nf = 0; nf < 4; ++nf) oacc[nf][r] *= ar;
      }
      l_run *= alpha;
      m_run = m_new;
    }

    float ls = 0.f;
#pragma unroll
    for (int mf = 0; mf < 4; ++mf) {
      u16x4 pb;
#pragma unroll
      for (int r = 0; r < 4; ++r) {
        float p = __builtin_amdgcn_exp2f(st[mf][r] - m_run);
        ls += p;
        pb[r] = f2bf_hw(p);
      }
      *(u16x4*)&Pw[lq * 72 + mf * 16 + lg * 4] = pb;  // P[q][key]
    }
    ls += __shfl_xor(ls, 16);
    ls += __shfl_xor(ls, 32);
    l_run += ls;
    asm volatile("s_waitcnt lgkmcnt(0)" ::: "memory");

    // O[q][dv] += P @ V
    __builtin_amdgcn_s_setprio(1);
#pragma unroll
    for (int ks = 0; ks < 2; ++ks) {
      bf16x8 pf = *(const bf16x8*)&Pw[lq * 72 + ks * 32 + lg * 8];
#pragma unroll
      for (int nf = 0; nf < 4; ++nf) {
        int row = nf * 16 + lq;
        bf16x8 vf = *(const bf16x8*)&Vs[row * 64 + (((ks * 4 + lg) ^ (row & 7)) * 8)];
        oacc[nf] = __builtin_amdgcn_mfma_f32_16x16x32_bf16(pf, vf, oacc[nf], 0, 0, 0);
      }
    }
    __builtin_amdgcn_s_setprio(0);
  }

  // normalize + store ctx (bf16, [B,S,E] layout)
#pragma unroll
  for (int r = 0; r < 4; ++r) {
    float lr = __shfl(l_run, lg * 4 + r);
    float inv = 1.f / lr;
#pragma unroll
    for (int nf = 0; nf < 4; ++nf) {
      ctx[((size_t)(b * S_) + q0 + wave * 16 + lg * 4 + r) * E_ + h * 64 + nf * 16 + lq] =
          f2bf_hw(oacc[nf][r] * inv);
    }
  }
}

// ---------------- launch -------------------------------------------------
extern "C" void kernel_launch(void* const* d_in, const int* in_sizes, int n_in,
                              void* d_out, int out_size, void* d_ws, size_t ws_size,
                              hipStream_t stream) {
  const float* h  = (const float*)d_in[0];
  const float* Wq = (const float*)d_in[1];
  const float* Wk = (const float*)d_in[2];
  const float* Wv = (const float*)d_in[3];
  const float* Wo = (const float*)d_in[4];
  float* out = (float*)d_out;
  char* ws = (char*)d_ws;

  const size_t SZ_H = (size_t)M_ * E_ * 2;   // 8 MiB
  const size_t SZ_W = (size_t)E_ * E_ * 2;   // 2 MiB
  unsigned short* hb  = (unsigned short*)(ws);
  unsigned short* wqb = (unsigned short*)(ws + SZ_H);
  unsigned short* wkb = (unsigned short*)(ws + SZ_H + SZ_W);
  unsigned short* wvb = (unsigned short*)(ws + SZ_H + 2 * SZ_W);
  unsigned short* wob = (unsigned short*)(ws + SZ_H + 3 * SZ_W);
  unsigned short* Qb  = (unsigned short*)(ws + SZ_H + 4 * SZ_W);
  unsigned short* Kb  = (unsigned short*)(ws + 2 * SZ_H + 4 * SZ_W);
  unsigned short* Vb  = (unsigned short*)(ws + 3 * SZ_H + 4 * SZ_W);
  unsigned short* VTb = hb;   // h no longer needed after QKV GEMMs
  unsigned short* Cb  = Vb;   // V no longer needed after transpose

  // one fused convert for h + all weights; fold 0.125*log2(e) into W_q
  const float QSCALE = 0.125f * 1.44269504f;
  cvt_all<<<8192, 256, 0, stream>>>(h, Wq, Wk, Wv, Wo, hb, QSCALE);

  // fused QKV projection: 3 blocks/CU instead of 1
  gemm_qkv<<<dim3(M_ / 128, 3 * E_ / 128), 256, 0, stream>>>(hb, wqb, wkb, wvb, Qb, Kb, Vb);

  transpose_v<<<dim3(S_ / 64, H_, B_), 256, 0, stream>>>(Vb, VTb);

  attn<<<dim3(S_ / 64, B_ * H_), 256, 0, stream>>>(Qb, Kb, VTb, Cb);

  gemm_out<<<dim3(M_ / 128, E_ / 128), 256, 0, stream>>>(Cb, wob, out);
}